// Round 16
// baseline (310.451 us; speedup 1.0000x reference)
//
#include <hip/hip_runtime.h>
#include <hip/hip_bf16.h>

// DNBN system, f16-MFMA, round 16.
// N=8, B=256, M=512, C=512, NH=8, DH=64, S=8, HC=64, T=3, OUT=100.
// T(3) < S(8) -> FIFO never evicts -> buf.mean == msum/8.
// Round 16: convfused 2-tap staging rounds (drains 9->5, barriers 18->10),
// LDS correctly sized this time: A = 2 x 16,384 B. 70,016 B total -> 2/CU.
// Everything else identical to R15 (302us).

typedef _Float16 f16;
typedef _Float16 f16x8 __attribute__((ext_vector_type(8)));
typedef _Float16 f16x4 __attribute__((ext_vector_type(4)));
typedef _Float16 f16x2 __attribute__((ext_vector_type(2)));
typedef float f32x4 __attribute__((ext_vector_type(4)));

#define GLOAD_LDS16(gsrc, ldst)                                                   \
  __builtin_amdgcn_global_load_lds(                                               \
      (const __attribute__((address_space(1))) void*)(gsrc),                      \
      (__attribute__((address_space(3))) void*)(ldst), 16, 0, 0)

// ---------------- transpose+convert tile body: [K][N] f32 -> [N][K] f16 (scaled)
__device__ __forceinline__ void tw64_body(
    const float* __restrict__ s, f16* __restrict__ d, int K, int N, float scale,
    int n0, int k0, int t)
{
  __shared__ float tile[64][65];
#pragma unroll
  for (int p = 0; p < 4; p++) {
    int idx = t + p * 256;
    int kk = idx >> 4, nq = (idx & 15) * 4;
    float4 v = *(const float4*)&s[(long)(k0 + kk) * N + n0 + nq];
    tile[kk][nq] = v.x; tile[kk][nq + 1] = v.y; tile[kk][nq + 2] = v.z; tile[kk][nq + 3] = v.w;
  }
  __syncthreads();
#pragma unroll
  for (int p = 0; p < 2; p++) {
    int idx = t + p * 256;
    int nn = idx >> 3, kc = (idx & 7) * 8;
    f16 o[8];
#pragma unroll
    for (int i = 0; i < 8; i++) o[i] = (f16)(tile[kc + i][nn] * scale);
    *(f16x8*)&d[(long)(n0 + nn) * K + k0 + kc] = *(const f16x8*)o;
  }
}

// 8-way batched transpose: z = sel*8 + e
// sel: 0=wq 1=wk 2=wv 3=wi 4=wr(x.125) 5=featw 6=wg 7=wc
__global__ __launch_bounds__(256) void twall_kernel(
    const float* __restrict__ wq, const float* __restrict__ wk,
    const float* __restrict__ wv, const float* __restrict__ wi,
    const float* __restrict__ wr, const float* __restrict__ fw,
    const float* __restrict__ wg, const float* __restrict__ wc,
    f16* __restrict__ wqT, f16* __restrict__ wiT,
    f16* __restrict__ wrT, f16* __restrict__ featwT, f16* __restrict__ wgT)
{
  int z = blockIdx.z, sel = z >> 3, e = z & 7;
  int n0 = blockIdx.x * 64, k0 = blockIdx.y * 64;
  const float* src;
  f16* dst;
  int K = 512, N = 512;
  float scale = 1.f;
  if (sel == 0)      { if (k0 >= 512) return; src = wq + (long)e * 262144; dst = wqT + (long)e * 262144; }
  else if (sel == 1) { if (k0 >= 512) return; src = wk + (long)e * 262144; dst = wqT + 2097152 + (long)e * 262144; }
  else if (sel == 2) { if (k0 >= 512) return; src = wv + (long)e * 262144; dst = wqT + 4194304 + (long)e * 262144; }
  else if (sel == 3) {
    N = 192; if (n0 >= 192 || k0 >= 512) return;
    src = wi + (long)e * 98304; dst = wiT + (long)e * 98304;
  } else if (sel == 4) {
    if (k0 >= 512) return;
    scale = 0.125f;
    src = wr + (long)e * 262144; dst = wrT + (long)e * 262144;
  } else if (sel == 5) {
    K = 128; if (k0 >= 128) return;
    src = fw + (long)e * 65536; dst = featwT + (long)e * 65536;
  } else if (sel == 6) {
    K = 1536;
    src = wg + (long)e * 786432; dst = wgT + (long)e * 786432;
  } else {
    K = 1536;
    src = wc + (long)e * 786432; dst = wgT + 6291456 + (long)e * 786432;
  }
  tw64_body(src, dst, K, N, scale, n0, k0, threadIdx.x);
}

// ---------------- merged small preps: wo->f16, conv2-w permute, conv1-w prep,
// wcls transpose, im2col xprep
__global__ __launch_bounds__(256) void smallprep_kernel(
    const float* __restrict__ wo, f16* __restrict__ wo16,
    const float* __restrict__ c2src, f16* __restrict__ c2dst,
    const float* __restrict__ w1src, f16* __restrict__ w1dst,
    const float* __restrict__ wcls, f16* __restrict__ wclsT,
    const float* __restrict__ x, f16* __restrict__ xp16)
{
  __shared__ __align__(16) float shmem[3072];
  int bid = blockIdx.x, t = threadIdx.x;
  if (bid < 1024) {
    long i = ((long)bid * 256 + t) * 8;
    float4 a = *(const float4*)&wo[i];
    float4 b = *(const float4*)&wo[i + 4];
    f16 o[8] = {(f16)a.x, (f16)a.y, (f16)a.z, (f16)a.w, (f16)b.x, (f16)b.y, (f16)b.z, (f16)b.w};
    *(f16x8*)&wo16[i] = *(const f16x8*)o;
  } else if (bid < 3328) {
    long i = (long)(bid - 1024) * 256 + t; // 589824
    int ci = i & 63; long r = i >> 6; int tap = r % 9; r /= 9; int co = r & 127; int n = (int)(r >> 7);
    c2dst[i] = (f16)c2src[(((long)(n * 128 + co) * 64 + ci) * 9) + tap];
  } else if (bid < 3392) {
    int i = (bid - 3328) * 256 + t; // 16384
    int j = i & 7, co = (i >> 3) & 63, slot = (i >> 9) & 3, e = i >> 11;
    int k = slot * 8 + j;
    w1dst[i] = (f16)((k < 27) ? w1src[(long)e * 1728 + co * 27 + k] : 0.f);
  } else if (bid < 3904) {
    // wcls transpose: [8][512][100] -> [8][128][512] f16 (pad 100->128)
    float (*tile)[33] = (float(*)[33])shmem;
    int bid2 = bid - 3392;
    int e = bid2 >> 6, ky = (bid2 >> 2) & 15, nx = bid2 & 3;
    int n0 = nx * 32, k0 = ky * 32;
    int tx = t & 31, ty = t >> 5;
    const float* s = wcls + (long)e * 51200;
    f16* d = wclsT + (long)e * 65536;
    for (int r = ty; r < 32; r += 8) {
      int k = k0 + r, n = n0 + tx;
      tile[r][tx] = (n < 100) ? s[(long)k * 100 + n] : 0.f;
    }
    __syncthreads();
    for (int r = ty; r < 32; r += 8) {
      int n = n0 + r, k = k0 + tx;
      d[(long)n * 512 + k] = (f16)tile[tx][r];
    }
  } else {
    // im2col: x[b] -> xp16[b][4 slot][256 pix][8], k padded 27->32
    float* xs = shmem;
    int b = bid - 3904;
    const float* xb = x + (long)b * 3072;
    for (int i = t; i < 768; i += 256) ((float4*)xs)[i] = ((const float4*)xb)[i];
    __syncthreads();
    int oy = t >> 4, ox = t & 15;
    f16 pv[32];
#pragma unroll
    for (int q = 27; q < 32; q++) pv[q] = (f16)0.f;
#pragma unroll
    for (int ci = 0; ci < 3; ci++)
#pragma unroll
      for (int ky = 0; ky < 3; ky++) {
        int iy = oy * 2 + ky;
#pragma unroll
        for (int kx = 0; kx < 3; kx++) {
          int ix = ox * 2 + kx;
          pv[ci * 9 + ky * 3 + kx] =
              (f16)((iy < 32 && ix < 32) ? xs[ci * 1024 + iy * 32 + ix] : 0.f);
        }
      }
    f16* ob = xp16 + (long)b * 8192;
#pragma unroll
    for (int c = 0; c < 4; c++) *(f16x8*)&ob[c * 2048 + t * 8] = *(const f16x8*)&pv[c * 8];
  }
}

// ---------------- bor[n][o] = (bo @ wr)[o]/8, K-parallel (16 lanes per output)
__global__ __launch_bounds__(256) void borprep2_kernel(
    const f16* __restrict__ wrT, const float* __restrict__ bo, float* __restrict__ bor32)
{
  int n = blockIdx.y, t = threadIdx.x;
  int og = blockIdx.x * 16 + (t >> 4), k16 = t & 15;
  const f16* row = wrT + (long)n * 262144 + (long)og * 512 + k16 * 32;
  const float* bp = bo + n * 512 + k16 * 32;
  float s = 0.f;
#pragma unroll
  for (int i = 0; i < 32; i += 8) {
    f16x8 v = *(const f16x8*)&row[i];
    float4 b0 = *(const float4*)&bp[i];
    float4 b1 = *(const float4*)&bp[i + 4];
    s = fmaf((float)v[0], b0.x, s); s = fmaf((float)v[1], b0.y, s);
    s = fmaf((float)v[2], b0.z, s); s = fmaf((float)v[3], b0.w, s);
    s = fmaf((float)v[4], b1.x, s); s = fmaf((float)v[5], b1.y, s);
    s = fmaf((float)v[6], b1.z, s); s = fmaf((float)v[7], b1.w, s);
  }
  s += __shfl_xor(s, 1); s += __shfl_xor(s, 2);
  s += __shfl_xor(s, 4); s += __shfl_xor(s, 8);
  if (k16 == 0) bor32[n * 512 + og] = s;
}

// ---------------- bias folds, K-parallel
__global__ __launch_bounds__(256) void biasfold2_kernel(
    const f16* __restrict__ wgT, const f16* __restrict__ wcT,
    const float* __restrict__ bg, const float* __restrict__ bc,
    const float* __restrict__ br, const float* __restrict__ bor32,
    float* __restrict__ bgr, float* __restrict__ vg2,
    float* __restrict__ bcr, float* __restrict__ vc2)
{
  int n = blockIdx.y, t = threadIdx.x;
  int og = blockIdx.x * 16 + (t >> 4), k16 = t & 15;
  const f16* gr = wgT + (long)n * 786432 + (long)og * 1536 + 1024 + k16 * 32;
  const f16* cr = wcT + (long)n * 786432 + (long)og * 1536 + 1024 + k16 * 32;
  const float* brp = br + n * 512 + k16 * 32;
  const float* bop = bor32 + n * 512 + k16 * 32;
  float s1g = 0.f, s2g = 0.f, s1c = 0.f, s2c = 0.f;
#pragma unroll
  for (int i = 0; i < 32; i += 8) {
    f16x8 gv = *(const f16x8*)&gr[i];
    f16x8 cv = *(const f16x8*)&cr[i];
#pragma unroll
    for (int q = 0; q < 8; q++) {
      float brm = brp[i + q], bom = bop[i + q];
      s1g = fmaf(brm, (float)gv[q], s1g); s2g = fmaf(bom, (float)gv[q], s2g);
      s1c = fmaf(brm, (float)cv[q], s1c); s2c = fmaf(bom, (float)cv[q], s2c);
    }
  }
#pragma unroll
  for (int o = 1; o < 16; o <<= 1) {
    s1g += __shfl_xor(s1g, o); s2g += __shfl_xor(s2g, o);
    s1c += __shfl_xor(s1c, o); s2c += __shfl_xor(s2c, o);
  }
  if (k16 == 0) {
    bgr[n * 512 + og] = bg[n * 512 + og] + s1g; vg2[n * 512 + og] = s2g;
    bcr[n * 512 + og] = bc[n * 512 + og] + s1c; vc2[n * 512 + og] = s2c;
  }
}

// ---------------- fused conv1(MFMA)+conv2(MFMA)+pool: one block per (b,e)
// 2-tap staging rounds: A = 2 x 16,384 B; drains 9->5. LDS 70,016 B (2/CU).
__global__ __launch_bounds__(256) void convfused_kernel(
    const f16* __restrict__ xp16, const f16* __restrict__ w1p, const float* __restrict__ b1,
    const f16* __restrict__ w2p, const float* __restrict__ b2, f16* __restrict__ pooled16)
{
  __shared__ __align__(16) char lds[70016];
  f16* Asub = (f16*)lds;                // 32,768 B: [2 tap][128 co][64 ci]
  f16* xpatch = (f16*)lds;              // 16KB alias (ph0-1, inside tap0 region)
  float* red = (float*)lds;             // 1KB alias (epilogue)
  float* bs1 = (float*)(lds + 32768);   // 256B
  f16* h1s = (f16*)(lds + 33024);       // 36,992B [289 pix][64 ci] swizzled
  f16* ws1 = (f16*)(lds + 33024);       // 4KB alias inside h1s (ph0-1)

  int b = blockIdx.x, e = blockIdx.y;
  int t = threadIdx.x, w = t >> 6, l = t & 63;

  const f16* xb = xp16 + (long)b * 8192;
#pragma unroll
  for (int c = 0; c < 4; c++)
    GLOAD_LDS16(xb + (w * 4 + c) * 512 + l * 8, &xpatch[(w * 4 + c) * 512]);
  GLOAD_LDS16(w1p + (long)e * 2048 + w * 512 + l * 8, &ws1[w * 512]);
  if (t < 64) bs1[t] = b1[e * 64 + t];
  asm volatile("s_waitcnt vmcnt(0)" ::: "memory");
  __syncthreads();

  // ph1: conv1 MFMA
  {
    int pw = w * 64;
    f16x8 a1[4], b1f[4];
#pragma unroll
    for (int i = 0; i < 4; i++)
      a1[i] = *(const f16x8*)&ws1[(l >> 4) * 512 + (i * 16 + (l & 15)) * 8];
#pragma unroll
    for (int jj = 0; jj < 4; jj++)
      b1f[jj] = *(const f16x8*)&xpatch[(l >> 4) * 2048 + (pw + jj * 16 + (l & 15)) * 8];
    __syncthreads(); // frag reads complete before h1s writes overwrite ws1 alias
    f32x4 acc1[4][4];
#pragma unroll
    for (int i = 0; i < 4; i++)
#pragma unroll
      for (int jj = 0; jj < 4; jj++)
        acc1[i][jj] = __builtin_amdgcn_mfma_f32_16x16x32_f16(
            a1[i], b1f[jj], (f32x4){0.f, 0.f, 0.f, 0.f}, 0, 0, 0);
#pragma unroll
    for (int i = 0; i < 4; i++) {
      int co0 = i * 16 + ((l >> 4) << 2);
      float bi0 = bs1[co0], bi1 = bs1[co0 + 1], bi2 = bs1[co0 + 2], bi3 = bs1[co0 + 3];
#pragma unroll
      for (int jj = 0; jj < 4; jj++) {
        int p2 = pw + jj * 16 + (l & 15);
        int oy2 = p2 >> 4, ox2 = p2 & 15;
        int p = oy2 * 17 + ox2;
        int fs = ((ox2 >> 1) + oy2) & 7;
        int slot = (co0 >> 3) ^ fs;
        f16x4 v;
        v[0] = (f16)fmaxf(acc1[i][jj][0] + bi0, 0.f);
        v[1] = (f16)fmaxf(acc1[i][jj][1] + bi1, 0.f);
        v[2] = (f16)fmaxf(acc1[i][jj][2] + bi2, 0.f);
        v[3] = (f16)fmaxf(acc1[i][jj][3] + bi3, 0.f);
        *(f16x4*)&h1s[p * 64 + slot * 8 + (co0 & 7)] = v;
      }
    }
  }
  if (t < 33) { // zero guard ring (row 16 + col 16)
    int gy = (t < 17) ? 16 : (t - 17);
    int gx = (t < 17) ? t : 16;
    int p = gy * 17 + gx;
    f16x8 zz = {};
#pragma unroll
    for (int g = 0; g < 8; g++) *(f16x8*)&h1s[p * 64 + g * 8] = zz;
  }

  // ph2: conv2 MFMA, 5 rounds x (up to) 2 taps per staging drain
  int waveR = w >> 1, waveC = w & 1;
  const f16* wbase = w2p + (long)e * 73728;
  f32x4 acc[4][2];
#pragma unroll
  for (int i = 0; i < 4; i++) {
    acc[i][0] = (f32x4){0.f, 0.f, 0.f, 0.f};
    acc[i][1] = (f32x4){0.f, 0.f, 0.f, 0.f};
  }
  for (int r = 0; r < 5; r++) {
    const int ntap = (r < 4) ? 2 : 1;
    __syncthreads(); // prev round A reads done (r=0: xpatch reads + h1s writes done)
    for (int q = 0; q < ntap; q++) {
      int tap = r * 2 + q;
#pragma unroll
      for (int c = 0; c < 4; c++) {
        int ch = w * 4 + c;
        int co = ch * 8 + (l >> 3);
        int g = (l & 7) ^ (co & 7);
        GLOAD_LDS16(wbase + ((long)co * 9 + tap) * 64 + g * 8,
                    &Asub[q * 8192 + ch * 512]);
      }
    }
    asm volatile("s_waitcnt vmcnt(0)" ::: "memory");
    __syncthreads();
    for (int q = 0; q < ntap; q++) {
      int tap = r * 2 + q;
      int ky = tap / 3, kx = tap - ky * 3;
      const f16* Ab = &Asub[q * 8192];
#pragma unroll
      for (int kk = 0; kk < 2; kk++) {
        f16x8 af[4], bf[2];
#pragma unroll
        for (int i = 0; i < 4; i++) {
          int row = waveR * 64 + i * 16 + (l & 15);
          int blk = (kk * 4 + (l >> 4)) ^ (row & 7);
          af[i] = *(const f16x8*)&Ab[row * 64 + blk * 8];
        }
#pragma unroll
        for (int j = 0; j < 2; j++) {
          int sp = waveC * 32 + j * 16 + (l & 15);
          int iy = (sp >> 3) * 2 + ky, ix = (sp & 7) * 2 + kx;
          int fs = ((ix >> 1) + iy) & 7;
          int blk = (kk * 4 + (l >> 4)) ^ fs;
          bf[j] = *(const f16x8*)&h1s[(iy * 17 + ix) * 64 + blk * 8];
        }
#pragma unroll
        for (int i = 0; i < 4; i++)
#pragma unroll
          for (int j = 0; j < 2; j++)
            acc[i][j] = __builtin_amdgcn_mfma_f32_16x16x32_f16(af[i], bf[j], acc[i][j], 0, 0, 0);
      }
    }
  }
  __syncthreads(); // last round's Asub reads done -> red alias safe
  const float* bn2 = b2 + e * 128;
#pragma unroll
  for (int i = 0; i < 4; i++) {
#pragma unroll
    for (int reg = 0; reg < 4; reg++) {
      int row = waveR * 64 + i * 16 + ((l >> 4) << 2) + reg;
      float bi = bn2[row];
      float s = fmaxf(acc[i][0][reg] + bi, 0.f) + fmaxf(acc[i][1][reg] + bi, 0.f);
      s += __shfl_xor(s, 1); s += __shfl_xor(s, 2);
      s += __shfl_xor(s, 4); s += __shfl_xor(s, 8);
      if ((l & 15) == 0) red[waveC * 128 + row] = s;
    }
  }
  __syncthreads();
  if (t < 128) {
    float v = (red[t] + red[128 + t]) * (1.f / 64.f);
    pooled16[((long)e * 256 + b) * 128 + t] = (f16)v;
  }
}

// ---------------- segmented f16-MFMA GEMM: MRx64 tile, 4 waves, per-seg outputs
struct SegsM {
  const f16* BT[4];
  const float* bias[4];
  f16* o16[4];
  f16* o16b[4];
  float* o32[4];
  long sBT[4], sBias[4], sO16[4], sO32[4];
  int ldo16[4], ldo32[4], act[4], segCols[4];
};

template <int MR>
__global__ __launch_bounds__(256) void gemmf16_kernel(
    const f16* __restrict__ A, long sA, int lda, SegsM segs, int K)
{
  constexpr int IW = MR / 32;
  __shared__ __align__(16) f16 Asub[2][MR * 64];
  __shared__ __align__(16) f16 Bsub[2][4096];
  int z = blockIdx.z;
  int rowBase = blockIdx.y * MR;
  int vcBase = blockIdx.x * 64;
  int seg = vcBase >> 9;
  int lcBase = vcBase & 511;
  const f16* An = A + (long)z * sA + (long)rowBase * lda;
  const f16* BTn = segs.BT[seg] + (long)z * segs.sBT[seg] + (long)lcBase * K;
  const float* biasN = segs.bias[seg] ? segs.bias[seg] + (long)z * segs.sBias[seg] : nullptr;
  int act = segs.act[seg];
  int segCols = segs.segCols[seg];
  int t = threadIdx.x, w = t >> 6, l = t & 63;
  int waveR = w >> 1, waveC = w & 1;
  f32x4 acc[IW][2];
#pragma unroll
  for (int i = 0; i < IW; i++) {
    acc[i][0] = (f32x4){0.f, 0.f, 0.f, 0.f};
    acc[i][1] = (f32x4){0.f, 0.f, 0.f, 0.f};
  }
  auto stage = [&](int buf, int kt) {
    int k0 = kt << 6;
#pragma unroll
    for (int c = 0; c < MR / 32; c++) {
      int ch = w * (MR / 32) + c;
      int row = ch * 8 + (l >> 3);
      int g = (l & 7) ^ (row & 7);
      GLOAD_LDS16(An + (long)row * lda + k0 + g * 8, &Asub[buf][ch * 512]);
    }
#pragma unroll
    for (int c = 0; c < 2; c++) {
      int ch = w * 2 + c;
      int col = ch * 8 + (l >> 3);
      int g = (l & 7) ^ (col & 7);
      GLOAD_LDS16(BTn + (long)col * K + k0 + g * 8, &Bsub[buf][ch * 512]);
    }
  };
  int nk = K >> 6;
  stage(0, 0);
  asm volatile("s_waitcnt vmcnt(0)" ::: "memory");
  __syncthreads();
  int cur = 0;
  for (int kt = 0; kt < nk; kt++) {
    if (kt + 1 < nk) stage(cur ^ 1, kt + 1);
#pragma unroll
    for (int kk = 0; kk < 2; kk++) {
      f16x8 af[IW], bf[2];
#pragma unroll
      for (int i = 0; i < IW; i++) {
        int row = waveR * (MR / 2) + i * 16 + (l & 15);
        int blk = (kk * 4 + (l >> 4)) ^ (row & 7);
        af[i] = *(const f16x8*)&Asub[cur][row * 64 + blk * 8];
      }
#pragma unroll
      for (int j = 0; j < 2; j++) {
        int col = waveC * 32 + j * 16 + (l & 15);
        int blk = (kk * 4 + (l >> 4)) ^ (col & 7);
        bf[j] = *(const f16x8*)&Bsub[cur][col * 64 + blk * 8];
      }
#pragma unroll
      for (int i = 0; i < IW; i++)
#pragma unroll
        for (int j = 0; j < 2; j++)
          acc[i][j] = __builtin_amdgcn_mfma_f32_16x16x32_f16(af[i], bf[j], acc[i][j], 0, 0, 0);
    }
    if (kt + 1 < nk) {
      asm volatile("s_waitcnt vmcnt(0)" ::: "memory");
      __syncthreads();
      cur ^= 1;
    }
  }
  f16* o16 = segs.o16[seg];
  f16* o16b = segs.o16b[seg];
  float* o32 = segs.o32[seg];
  long sO16 = segs.sO16[seg], sO32 = segs.sO32[seg];
  int ldo16 = segs.ldo16[seg], ldo32 = segs.ldo32[seg];
#pragma unroll
  for (int i = 0; i < IW; i++) {
    int rb = rowBase + waveR * (MR / 2) + i * 16 + ((l >> 4) << 2);
#pragma unroll
    for (int j = 0; j < 2; j++) {
      int lc = lcBase + waveC * 32 + j * 16 + (l & 15);
      if (lc >= segCols) continue;
      float bv = biasN ? biasN[lc] : 0.f;
#pragma unroll
      for (int reg = 0; reg < 4; reg++) {
        float v = acc[i][j][reg] + bv;
        if (act == 1) v = fmaxf(v, 0.f);
        else if (act == 2) v = 1.f / (1.f + __expf(-v));
        else if (act == 3) v = tanhf(v);
        long rr = rb + reg;
        if (o16) o16[(long)z * sO16 + rr * ldo16 + lc] = (f16)v;
        if (o16b) o16b[(long)z * sO16 + rr * ldo16 + lc] = (f16)v;
        if (o32) o32[(long)z * sO32 + rr * ldo32 + lc] = v;
      }
    }
  }
}

// ---------------- per-step fused GRU + gates + 8-node attention (512 threads)
__global__ __launch_bounds__(512) void step_kernel(
    const f16* __restrict__ qkv16, const float* __restrict__ gi32,
    const float* __restrict__ wh, const float* __restrict__ bh,
    float* __restrict__ cs, const float* __restrict__ sw, const float* __restrict__ sb,
    const float* __restrict__ rw, const float* __restrict__ rb,
    const float* __restrict__ aw, const float* __restrict__ abb,
    const float* __restrict__ edge,
    float* __restrict__ msgsum32, f16* __restrict__ msgsum16, int step)
{
  int b = blockIdx.x, t = threadIdx.x;
  __shared__ float qs[8 * 520], ks[8 * 520];
  __shared__ f16 vs16[8 * 520];
  __shared__ float csh[512];
  __shared__ float sc[512];
  __shared__ float se[8], re[8], edg[64], abl[64];

  for (int i = t; i < 2048; i += 512) {
    int nn = i >> 8, c2 = (i & 255) * 2;
    int h = c2 >> 6, d = c2 & 63;
    long base = ((long)nn * 256 + b) * 1536 + c2;
    int la = nn * 520 + h * 65 + d;
    f16x2 qv = *(const f16x2*)&qkv16[base];
    f16x2 kv = *(const f16x2*)&qkv16[base + 512];
    *(f16x2*)&vs16[la] = *(const f16x2*)&qkv16[base + 1024];
    qs[la] = (float)qv[0]; qs[la + 1] = (float)qv[1];
    ks[la] = (float)kv[0]; ks[la + 1] = (float)kv[1];
  }
  if (t >= 448) edg[t - 448] = edge[t - 448];
  int n = t >> 6, hc = t & 63;
  if (step > 0) csh[t] = cs[((long)n * 256 + b) * 64 + hc];
  __syncthreads();

  float c0 = (step > 0) ? csh[t] : 0.f;
  float g0 = bh[n * 192 + hc], g1 = bh[n * 192 + 64 + hc], g2 = bh[n * 192 + 128 + hc];
  if (step > 0) {
    const float* whn = wh + (long)n * 12288;
    for (int k = 0; k < 64; k++) {
      float cv = csh[n * 64 + k];
      g0 = fmaf(cv, whn[k * 192 + hc], g0);
      g1 = fmaf(cv, whn[k * 192 + 64 + hc], g1);
      g2 = fmaf(cv, whn[k * 192 + 128 + hc], g2);
    }
  }
  const float* gi = gi32 + ((long)n * 256 + b) * 192;
  float zg = 1.f / (1.f + __expf(-(gi[hc] + g0)));
  float rg = 1.f / (1.f + __expf(-(gi[64 + hc] + g1)));
  float ng = tanhf(gi[128 + hc] + rg * g2);
  float cn = (1.f - zg) * ng + zg * c0;
  cs[((long)n * 256 + b) * 64 + hc] = cn;
  {
    float ps = cn * sw[n * 64 + hc];
    float pr = cn * rw[n * 64 + hc];
#pragma unroll
    for (int o = 32; o; o >>= 1) { ps += __shfl_xor(ps, o); pr += __shfl_xor(pr, o); }
    if (hc == 0) {
      se[n] = 1.f / (1.f + __expf(-(ps + sb[n])));
      re[n] = 1.f / (1.f + __expf(-(pr + rb[n])));
    }
#pragma unroll
    for (int kk = 0; kk < 8; kk++) {
      float pa = cn * aw[(n * 64 + hc) * 8 + kk];
#pragma unroll
      for (int o = 32; o; o >>= 1) pa += __shfl_xor(pa, o);
      if (hc == 0) abl[n * 8 + kk] = pa + abb[n * 8 + kk];
    }
  }
  __syncthreads();

  {
    int i = t >> 6, j = (t >> 3) & 7, h = t & 7;
    const float* qp = &qs[i * 520 + h * 65];
    const float* kp = &ks[j * 520 + h * 65];
    float s = 0.f;
#pragma unroll
    for (int d = 0; d < 64; d++) s = fmaf(qp[d], kp[d], s);
    sc[t] = s * 0.125f + edg[i * 8 + j] + abl[i * 8 + h];
  }
  __syncthreads();
  if (t < 64) {
    int i = t >> 3, h = t & 7;
    float mx = -1e30f;
#pragma unroll
    for (int j = 0; j < 8; j++) mx = fmaxf(mx, sc[(i << 6) + (j << 3) + h]);
    float e[8], sm = 0.f;
#pragma unroll
    for (int j = 0; j < 8; j++) { e[j] = __expf(sc[(i << 6) + (j << 3) + h] - mx); sm += e[j]; }
    float inv = re[i] / sm;
#pragma unroll
    for (int j = 0; j < 8; j++) sc[(i << 6) + (j << 3) + h] = e[j] * inv * se[j];
  }
  __syncthreads();
  for (int idx = t; idx < 4096; idx += 512) {
    int i = idx >> 9, c = idx & 511, h = c >> 6, d = c & 63;
    float s = 0.f;
#pragma unroll
    for (int j = 0; j < 8; j++)
      s = fmaf(sc[(i << 6) + (j << 3) + h], (float)vs16[j * 520 + h * 65 + d], s);
    long oi = ((long)i * 256 + b) * 512 + c;
    float nv = (step == 0) ? s : (msgsum32[oi] + s);
    msgsum32[oi] = nv;
    msgsum16[oi] = (f16)nv;
  }
}

// ---------------- fused gate GEMM + h-update (64-row tiles)
__global__ __launch_bounds__(256) void gatefused_kernel(
    const f16* __restrict__ h16cur, const f16* __restrict__ feats16,
    const f16* __restrict__ msgsum16,
    const f16* __restrict__ wgT, const f16* __restrict__ wcT,
    const f16* __restrict__ WeffGT, const f16* __restrict__ WeffCT,
    const float* __restrict__ bgr, const float* __restrict__ vg2,
    const float* __restrict__ bcr, const float* __restrict__ vc2,
    float* __restrict__ h32, f16* __restrict__ h16next, float tp1)
{
  __shared__ __align__(16) f16 Asub[2][4096];
  __shared__ __align__(16) f16 Bgs[2][4096];
  __shared__ __align__(16) f16 Bcs[2][4096];
  int z = blockIdx.z;
  int rowBase = blockIdx.y * 64;
  int colBase = blockIdx.x * 64;
  int t = threadIdx.x, w = t >> 6, l = t & 63;
  int waveR = w >> 1, waveC = w & 1;
  f32x4 accG[2][2], accC[2][2];
#pragma unroll
  for (int i = 0; i < 2; i++)
#pragma unroll
    for (int j = 0; j < 2; j++) {
      accG[i][j] = (f32x4){0.f, 0.f, 0.f, 0.f};
      accC[i][j] = (f32x4){0.f, 0.f, 0.f, 0.f};
    }

  auto stage = [&](int buf, int kt) {
    const f16* asrc;
    if (kt < 8)       asrc = h16cur  + (long)z * 131072 + kt * 64;
    else if (kt < 16) asrc = feats16 + (long)z * 131072 + (kt - 8) * 64;
    else              asrc = msgsum16 + (long)z * 131072 + (kt - 16) * 64;
#pragma unroll
    for (int c = 0; c < 2; c++) {
      int ch = w * 2 + c;
      int row = ch * 8 + (l >> 3);
      int g = (l & 7) ^ (row & 7);
      GLOAD_LDS16(asrc + (long)(rowBase + row) * 512 + g * 8, &Asub[buf][ch * 512]);
    }
#pragma unroll
    for (int c = 0; c < 2; c++) {
      int ch = w * 2 + c;
      int cl = ch * 8 + (l >> 3);
      int g = (l & 7) ^ (cl & 7);
      const f16 *bgsrc, *bcsrc;
      if (kt < 16) {
        bgsrc = wgT + (long)z * 786432 + (long)(colBase + cl) * 1536 + kt * 64 + g * 8;
        bcsrc = wcT + (long)z * 786432 + (long)(colBase + cl) * 1536 + kt * 64 + g * 8;
      } else {
        bgsrc = WeffGT + (long)z * 262144 + (long)(colBase + cl) * 512 + (kt - 16) * 64 + g * 8;
        bcsrc = WeffCT + (long)z * 262144 + (long)(colBase + cl) * 512 + (kt - 16) * 64 + g * 8;
      }
      GLOAD_LDS16(bgsrc, &Bgs[buf][ch * 512]);
      GLOAD_LDS16(bcsrc, &Bcs[buf][ch * 512]);
    }
  };
  stage(0, 0);
  asm volatile("s_waitcnt vmcnt(0)" ::: "memory");
  __syncthreads();
  int cur = 0;
  for (int kt = 0; kt < 24; kt++) {
    if (kt + 1 < 24) stage(cur ^ 1, kt + 1);
#pragma unroll
    for (int kk = 0; kk < 2; kk++) {
      f16x8 af[2], bgf[2], bcf[2];
#pragma unroll
      for (int i = 0; i < 2; i++) {
        int row = waveR * 32 + i * 16 + (l & 15);
        int blk = (kk * 4 + (l >> 4)) ^ (row & 7);
        af[i] = *(const f16x8*)&Asub[cur][row * 64 + blk * 8];
      }
#pragma unroll
      for (int j = 0; j < 2; j++) {
        int cl = waveC * 32 + j * 16 + (l & 15);
        int blk = (kk * 4 + (l >> 4)) ^ (cl & 7);
        bgf[j] = *(const f16x8*)&Bgs[cur][cl * 64 + blk * 8];
        bcf[j] = *(const f16x8*)&Bcs[cur][cl * 64 + blk * 8];
      }
#pragma unroll
      for (int i = 0; i < 2; i++)
#pragma unroll
        for (int j = 0; j < 2; j++) {
          accG[i][j] = __builtin_amdgcn_mfma_f32_16x16x32_f16(af[i], bgf[j], accG[i][j], 0, 0, 0);
          accC[i][j] = __builtin_amdgcn_mfma_f32_16x16x32_f16(af[i], bcf[j], accC[i][j], 0, 0, 0);
        }
    }
    if (kt + 1 < 24) {
      asm volatile("s_waitcnt vmcnt(0)" ::: "memory");
      __syncthreads();
      cur ^= 1;
    }
  }
#pragma unroll
  for (int i = 0; i < 2; i++) {
    int rb = rowBase + waveR * 32 + i * 16 + ((l >> 4) << 2);
#pragma unroll
    for (int j = 0; j < 2; j++) {
      int col = colBase + waveC * 32 + j * 16 + (l & 15);
      float bG = bgr[z * 512 + col] + tp1 * vg2[z * 512 + col];
      float bC = bcr[z * 512 + col] + tp1 * vc2[z * 512 + col];
#pragma unroll
      for (int reg = 0; reg < 4; reg++) {
        int row = rb + reg;
        float g = 1.f / (1.f + __expf(-(accG[i][j][reg] + bG)));
        float cd = tanhf(accC[i][j][reg] + bC);
        long hidx = ((long)z * 256 + row) * 512 + col;
        float h = h32[hidx];
        float nh = (1.f - g) * h + g * cd;
        h32[hidx] = nh;
        h16next[hidx] = (f16)nh;
      }
    }
  }
}

extern "C" void kernel_launch(void* const* d_in, const int* in_sizes, int n_in,
                              void* d_out, int out_size, void* d_ws, size_t ws_size,
                              hipStream_t stream)
{
  (void)in_sizes; (void)n_in; (void)out_size;
  const float* x        = (const float*)d_in[0];
  const float* conv1_w  = (const float*)d_in[1];
  const float* conv1_b  = (const float*)d_in[2];
  const float* conv2_w  = (const float*)d_in[3];
  const float* conv2_b  = (const float*)d_in[4];
  const float* feat_w   = (const float*)d_in[5];
  const float* feat_b   = (const float*)d_in[6];
  const float* ctrl_wi  = (const float*)d_in[7];
  const float* ctrl_wh  = (const float*)d_in[8];
  const float* ctrl_bi  = (const float*)d_in[9];
  const float* ctrl_bh  = (const float*)d_in[10];
  const float* send_w   = (const float*)d_in[11];
  const float* send_b   = (const float*)d_in[12];
  const float* recv_w   = (const float*)d_in[13];
  const float* recv_b   = (const float*)d_in[14];
  const float* abias_w  = (const float*)d_in[15];
  const float* abias_b  = (const float*)d_in[16];
  const float* wq       = (const float*)d_in[17];
  const float* wk       = (const float*)d_in[18];
  const float* wv       = (const float*)d_in[19];
  const float* wo       = (const float*)d_in[20];
  const float* bo       = (const float*)d_in[21];
  const float* edge     = (const float*)d_in[22];
  const float* wr       = (const float*)d_in[23];
  const float* br       = (const float*)d_in[24];
  const float* wg       = (const float*)d_in[25];
  const float* bg       = (const float*)d_in[26];
  const float* wc       = (const float*)d_in[27];
  const float* bc       = (const float*)d_in[28];
  const float* wcls     = (const float*)d_in[29];
  const float* bcls     = (const float*)d_in[30];

  // ---- workspace layout
  float* f32b = (float*)d_ws;
  float* h32      = f32b;             // 1,048,576
  float* gi32     = f32b + 1048576;   //   393,216
  float* msgsum32 = f32b + 1441792;   // 1,048,576
  float* cs       = f32b + 2490368;   //   131,072
  float* bor32    = f32b + 2621440;   //     4,096
  float* bgr      = f32b + 2625536;   //     4,096
  float* vg2b     = f32b + 2629632;   //     4,096
  float* bcr      = f32b + 2633728;   //     4,096
  float* vc2b     = f32b + 2637824;   //     4,096
  f16* hb = (f16*)(f32b + 2641920);
  f16* pooled16 = hb;                 //   262,144
  f16* h16a     = hb + 262144;        // 1,048,576
  f16* h16b     = hb + 1310720;       // 1,048,576
  f16* feats16  = hb + 2359296;       // 1,048,576
  f16* msgsum16 = hb + 3407872;       // 1,048,576
  f16* qkv16    = hb + 4456448;       // 3,145,728
  f16* wqT      = hb + 7602176;       // 6,291,456 (wq|wk|wv)
  f16* wiT      = hb + 13893632;      //   786,432
  f16* featwT   = hb + 14680064;      //   524,288
  f16* wrT      = hb + 15204352;      // 2,097,152 (x0.125)
  f16* wgT      = hb + 17301504;      // 6,291,456 (wcT contiguous)
  f16* wcT      = hb + 23592960;      // 6,291,456
  f16* c2wp     = hb + 29884416;      //   589,824
  f16* wo16     = hb + 30474240;      // 2,097,152
  f16* P        = hb + 32571392;      // 2,097,152
  f16* P2       = hb + 34668544;      // 2,097,152
  f16* WeffGT   = hb + 36765696;      // 2,097,152
  f16* WeffCT   = hb + 38862848;      // 2,097,152
  f16* w1p      = hb + 40960000;      //    16,384
  f16* xp16     = hb + 40976384;      // 2,097,152
  f16* wclsT    = hb + 43073536;      //   524,288
  // total = 10,567,680 + 87,195,648 = 97,763,328 B
  if (ws_size < 97763328ull) return;

  f16* hbuf[2] = {h16a, h16b};

  // ---- prep (17 launches total)
  twall_kernel<<<dim3(8, 24, 64), 256, 0, stream>>>(
      wq, wk, wv, ctrl_wi, wr, feat_w, wg, wc, wqT, wiT, wrT, featwT, wgT);
  smallprep_kernel<<<4160, 256, 0, stream>>>(wo, wo16, conv2_w, c2wp, conv1_w, w1p,
                                             wcls, wclsT, x, xp16);
  borprep2_kernel<<<dim3(32, 8), 256, 0, stream>>>(wrT, bo, bor32);
  biasfold2_kernel<<<dim3(32, 8), 256, 0, stream>>>(wgT, wcT, bg, bc, br, bor32,
                                                    bgr, vg2b, bcr, vc2b);
  // P[c][m] = sum_k wo[c][k]*wr[k][m]/8  (mirror into P2 for z=8..15 reads)
  {
    SegsM s{};
    s.BT[0] = wrT; s.sBT[0] = 262144;
    s.o16[0] = P; s.o16b[0] = P2; s.sO16[0] = 262144; s.ldo16[0] = 512;
    s.segCols[0] = 512;
    gemmf16_kernel<64><<<dim3(8, 8, 8), 256, 0, stream>>>(wo16, 262144L, 512, s, 512);
  }
  // Weff{G,C}T[o][c] = sum_m wg/wc_r[m][o]*P[c][m]
  {
    SegsM s{};
    s.BT[0] = P; s.sBT[0] = 262144;
    s.o16[0] = WeffGT; s.sO16[0] = 262144; s.ldo16[0] = 512;
    s.segCols[0] = 512;
    gemmf16_kernel<64><<<dim3(8, 8, 16), 256, 0, stream>>>(wgT + 1024, 786432L, 1536, s, 512);
  }

  // ---- feature extraction -> pooled16
  convfused_kernel<<<dim3(256, 8), 256, 0, stream>>>(xp16, w1p, conv1_b, c2wp, conv2_b, pooled16);

  // feats = relu(pooled @ feat_w + b) -> feats16; h-init -> h16a + h32
  {
    SegsM s{};
    s.BT[0] = featwT; s.sBT[0] = 65536; s.bias[0] = feat_b; s.sBias[0] = 512; s.act[0] = 1;
    s.o16[0] = feats16; s.o16b[0] = h16a; s.sO16[0] = 131072; s.ldo16[0] = 512;
    s.o32[0] = h32; s.sO32[0] = 131072; s.ldo32[0] = 512;
    s.segCols[0] = 512;
    gemmf16_kernel<128><<<dim3(8, 2, 8), 256, 0, stream>>>(pooled16, 32768L, 128, s, 128);
  }

  for (int step = 0; step < 3; step++) {
    // q|k|v (f16) + gi (f32) = h @ {wq,wk,wv,ctrl_wi}
    {
      SegsM s{};
      s.BT[0] = wqT;            s.sBT[0] = 262144;
      s.BT[1] = wqT + 2097152;  s.sBT[1] = 262144;
      s.BT[2] = wqT + 4194304;  s.sBT[2] = 262144;
      s.BT[3] = wiT;            s.sBT[3] = 98304;
      s.bias[3] = ctrl_bi; s.sBias[3] = 192;
      s.o16[0] = qkv16;        s.sO16[0] = 393216; s.ldo16[0] = 1536;
      s.o16[1] = qkv16 + 512;  s.sO16[1] = 393216; s.ldo16[1] = 1536;
      s.o16[2] = qkv16 + 1024; s.sO16[2] = 393216; s.ldo16[2] = 1536;
      s.o32[3] = gi32; s.sO32[3] = 49152; s.ldo32[3] = 192;
      s.segCols[0] = 512; s.segCols[1] = 512; s.segCols[2] = 512; s.segCols[3] = 192;
      gemmf16_kernel<128><<<dim3(27, 2, 8), 256, 0, stream>>>(hbuf[step & 1], 131072L, 512, s, 512);
    }
    step_kernel<<<256, 512, 0, stream>>>(
        qkv16, gi32, ctrl_wh, ctrl_bh, cs, send_w, send_b, recv_w, recv_b,
        abias_w, abias_b, edge, msgsum32, msgsum16, step);
    gatefused_kernel<<<dim3(8, 4, 8), 256, 0, stream>>>(
        hbuf[step & 1], feats16, msgsum16, wgT, wcT, WeffGT, WeffCT,
        bgr, vg2b, bcr, vc2b, h32, hbuf[(step + 1) & 1], (float)(step + 1));
  }
  // classifier: logits = h @ wclsT + bcls (f16 MFMA, fp32 out)
  {
    SegsM s{};
    s.BT[0] = wclsT; s.sBT[0] = 65536;
    s.bias[0] = bcls; s.sBias[0] = 100;
    s.o32[0] = (float*)d_out; s.sO32[0] = 25600; s.ldo32[0] = 100;
    s.segCols[0] = 100;
    gemmf16_kernel<128><<<dim3(2, 2, 8), 256, 0, stream>>>(hbuf[1], 131072L, 512, s, 512);
  }
}

// Round 17
// 302.012 us; speedup vs baseline: 1.0279x; 1.0279x over previous
//
#include <hip/hip_runtime.h>
#include <hip/hip_bf16.h>

// DNBN system, f16-MFMA, round 17 (revert to R15's best-measured 302.0us).
// N=8, B=256, M=512, C=512, NH=8, DH=64, S=8, HC=64, T=3, OUT=100.
// T(3) < S(8) -> FIFO never evicts -> buf.mean == msum/8.
// R16's 2-tap rounds regressed (drain savings < 3->2 blocks/CU occupancy loss);
// convfused restored to the 53.6KB / 3 blocks/CU / 9-tap __syncthreads form.

typedef _Float16 f16;
typedef _Float16 f16x8 __attribute__((ext_vector_type(8)));
typedef _Float16 f16x4 __attribute__((ext_vector_type(4)));
typedef _Float16 f16x2 __attribute__((ext_vector_type(2)));
typedef float f32x4 __attribute__((ext_vector_type(4)));

#define GLOAD_LDS16(gsrc, ldst)                                                   \
  __builtin_amdgcn_global_load_lds(                                               \
      (const __attribute__((address_space(1))) void*)(gsrc),                      \
      (__attribute__((address_space(3))) void*)(ldst), 16, 0, 0)

// ---------------- transpose+convert tile body: [K][N] f32 -> [N][K] f16 (scaled)
__device__ __forceinline__ void tw64_body(
    const float* __restrict__ s, f16* __restrict__ d, int K, int N, float scale,
    int n0, int k0, int t)
{
  __shared__ float tile[64][65];
#pragma unroll
  for (int p = 0; p < 4; p++) {
    int idx = t + p * 256;
    int kk = idx >> 4, nq = (idx & 15) * 4;
    float4 v = *(const float4*)&s[(long)(k0 + kk) * N + n0 + nq];
    tile[kk][nq] = v.x; tile[kk][nq + 1] = v.y; tile[kk][nq + 2] = v.z; tile[kk][nq + 3] = v.w;
  }
  __syncthreads();
#pragma unroll
  for (int p = 0; p < 2; p++) {
    int idx = t + p * 256;
    int nn = idx >> 3, kc = (idx & 7) * 8;
    f16 o[8];
#pragma unroll
    for (int i = 0; i < 8; i++) o[i] = (f16)(tile[kc + i][nn] * scale);
    *(f16x8*)&d[(long)(n0 + nn) * K + k0 + kc] = *(const f16x8*)o;
  }
}

// 8-way batched transpose: z = sel*8 + e
// sel: 0=wq 1=wk 2=wv 3=wi 4=wr(x.125) 5=featw 6=wg 7=wc
__global__ __launch_bounds__(256) void twall_kernel(
    const float* __restrict__ wq, const float* __restrict__ wk,
    const float* __restrict__ wv, const float* __restrict__ wi,
    const float* __restrict__ wr, const float* __restrict__ fw,
    const float* __restrict__ wg, const float* __restrict__ wc,
    f16* __restrict__ wqT, f16* __restrict__ wiT,
    f16* __restrict__ wrT, f16* __restrict__ featwT, f16* __restrict__ wgT)
{
  int z = blockIdx.z, sel = z >> 3, e = z & 7;
  int n0 = blockIdx.x * 64, k0 = blockIdx.y * 64;
  const float* src;
  f16* dst;
  int K = 512, N = 512;
  float scale = 1.f;
  if (sel == 0)      { if (k0 >= 512) return; src = wq + (long)e * 262144; dst = wqT + (long)e * 262144; }
  else if (sel == 1) { if (k0 >= 512) return; src = wk + (long)e * 262144; dst = wqT + 2097152 + (long)e * 262144; }
  else if (sel == 2) { if (k0 >= 512) return; src = wv + (long)e * 262144; dst = wqT + 4194304 + (long)e * 262144; }
  else if (sel == 3) {
    N = 192; if (n0 >= 192 || k0 >= 512) return;
    src = wi + (long)e * 98304; dst = wiT + (long)e * 98304;
  } else if (sel == 4) {
    if (k0 >= 512) return;
    scale = 0.125f;
    src = wr + (long)e * 262144; dst = wrT + (long)e * 262144;
  } else if (sel == 5) {
    K = 128; if (k0 >= 128) return;
    src = fw + (long)e * 65536; dst = featwT + (long)e * 65536;
  } else if (sel == 6) {
    K = 1536;
    src = wg + (long)e * 786432; dst = wgT + (long)e * 786432;
  } else {
    K = 1536;
    src = wc + (long)e * 786432; dst = wgT + 6291456 + (long)e * 786432;
  }
  tw64_body(src, dst, K, N, scale, n0, k0, threadIdx.x);
}

// ---------------- merged small preps: wo->f16, conv2-w permute, conv1-w prep,
// wcls transpose, im2col xprep
__global__ __launch_bounds__(256) void smallprep_kernel(
    const float* __restrict__ wo, f16* __restrict__ wo16,
    const float* __restrict__ c2src, f16* __restrict__ c2dst,
    const float* __restrict__ w1src, f16* __restrict__ w1dst,
    const float* __restrict__ wcls, f16* __restrict__ wclsT,
    const float* __restrict__ x, f16* __restrict__ xp16)
{
  __shared__ __align__(16) float shmem[3072];
  int bid = blockIdx.x, t = threadIdx.x;
  if (bid < 1024) {
    long i = ((long)bid * 256 + t) * 8;
    float4 a = *(const float4*)&wo[i];
    float4 b = *(const float4*)&wo[i + 4];
    f16 o[8] = {(f16)a.x, (f16)a.y, (f16)a.z, (f16)a.w, (f16)b.x, (f16)b.y, (f16)b.z, (f16)b.w};
    *(f16x8*)&wo16[i] = *(const f16x8*)o;
  } else if (bid < 3328) {
    long i = (long)(bid - 1024) * 256 + t; // 589824
    int ci = i & 63; long r = i >> 6; int tap = r % 9; r /= 9; int co = r & 127; int n = (int)(r >> 7);
    c2dst[i] = (f16)c2src[(((long)(n * 128 + co) * 64 + ci) * 9) + tap];
  } else if (bid < 3392) {
    int i = (bid - 3328) * 256 + t; // 16384
    int j = i & 7, co = (i >> 3) & 63, slot = (i >> 9) & 3, e = i >> 11;
    int k = slot * 8 + j;
    w1dst[i] = (f16)((k < 27) ? w1src[(long)e * 1728 + co * 27 + k] : 0.f);
  } else if (bid < 3904) {
    // wcls transpose: [8][512][100] -> [8][128][512] f16 (pad 100->128)
    float (*tile)[33] = (float(*)[33])shmem;
    int bid2 = bid - 3392;
    int e = bid2 >> 6, ky = (bid2 >> 2) & 15, nx = bid2 & 3;
    int n0 = nx * 32, k0 = ky * 32;
    int tx = t & 31, ty = t >> 5;
    const float* s = wcls + (long)e * 51200;
    f16* d = wclsT + (long)e * 65536;
    for (int r = ty; r < 32; r += 8) {
      int k = k0 + r, n = n0 + tx;
      tile[r][tx] = (n < 100) ? s[(long)k * 100 + n] : 0.f;
    }
    __syncthreads();
    for (int r = ty; r < 32; r += 8) {
      int n = n0 + r, k = k0 + tx;
      d[(long)n * 512 + k] = (f16)tile[tx][r];
    }
  } else {
    // im2col: x[b] -> xp16[b][4 slot][256 pix][8], k padded 27->32
    float* xs = shmem;
    int b = bid - 3904;
    const float* xb = x + (long)b * 3072;
    for (int i = t; i < 768; i += 256) ((float4*)xs)[i] = ((const float4*)xb)[i];
    __syncthreads();
    int oy = t >> 4, ox = t & 15;
    f16 pv[32];
#pragma unroll
    for (int q = 27; q < 32; q++) pv[q] = (f16)0.f;
#pragma unroll
    for (int ci = 0; ci < 3; ci++)
#pragma unroll
      for (int ky = 0; ky < 3; ky++) {
        int iy = oy * 2 + ky;
#pragma unroll
        for (int kx = 0; kx < 3; kx++) {
          int ix = ox * 2 + kx;
          pv[ci * 9 + ky * 3 + kx] =
              (f16)((iy < 32 && ix < 32) ? xs[ci * 1024 + iy * 32 + ix] : 0.f);
        }
      }
    f16* ob = xp16 + (long)b * 8192;
#pragma unroll
    for (int c = 0; c < 4; c++) *(f16x8*)&ob[c * 2048 + t * 8] = *(const f16x8*)&pv[c * 8];
  }
}

// ---------------- bor[n][o] = (bo @ wr)[o]/8, K-parallel (16 lanes per output)
__global__ __launch_bounds__(256) void borprep2_kernel(
    const f16* __restrict__ wrT, const float* __restrict__ bo, float* __restrict__ bor32)
{
  int n = blockIdx.y, t = threadIdx.x;
  int og = blockIdx.x * 16 + (t >> 4), k16 = t & 15;
  const f16* row = wrT + (long)n * 262144 + (long)og * 512 + k16 * 32;
  const float* bp = bo + n * 512 + k16 * 32;
  float s = 0.f;
#pragma unroll
  for (int i = 0; i < 32; i += 8) {
    f16x8 v = *(const f16x8*)&row[i];
    float4 b0 = *(const float4*)&bp[i];
    float4 b1 = *(const float4*)&bp[i + 4];
    s = fmaf((float)v[0], b0.x, s); s = fmaf((float)v[1], b0.y, s);
    s = fmaf((float)v[2], b0.z, s); s = fmaf((float)v[3], b0.w, s);
    s = fmaf((float)v[4], b1.x, s); s = fmaf((float)v[5], b1.y, s);
    s = fmaf((float)v[6], b1.z, s); s = fmaf((float)v[7], b1.w, s);
  }
  s += __shfl_xor(s, 1); s += __shfl_xor(s, 2);
  s += __shfl_xor(s, 4); s += __shfl_xor(s, 8);
  if (k16 == 0) bor32[n * 512 + og] = s;
}

// ---------------- bias folds, K-parallel
__global__ __launch_bounds__(256) void biasfold2_kernel(
    const f16* __restrict__ wgT, const f16* __restrict__ wcT,
    const float* __restrict__ bg, const float* __restrict__ bc,
    const float* __restrict__ br, const float* __restrict__ bor32,
    float* __restrict__ bgr, float* __restrict__ vg2,
    float* __restrict__ bcr, float* __restrict__ vc2)
{
  int n = blockIdx.y, t = threadIdx.x;
  int og = blockIdx.x * 16 + (t >> 4), k16 = t & 15;
  const f16* gr = wgT + (long)n * 786432 + (long)og * 1536 + 1024 + k16 * 32;
  const f16* cr = wcT + (long)n * 786432 + (long)og * 1536 + 1024 + k16 * 32;
  const float* brp = br + n * 512 + k16 * 32;
  const float* bop = bor32 + n * 512 + k16 * 32;
  float s1g = 0.f, s2g = 0.f, s1c = 0.f, s2c = 0.f;
#pragma unroll
  for (int i = 0; i < 32; i += 8) {
    f16x8 gv = *(const f16x8*)&gr[i];
    f16x8 cv = *(const f16x8*)&cr[i];
#pragma unroll
    for (int q = 0; q < 8; q++) {
      float brm = brp[i + q], bom = bop[i + q];
      s1g = fmaf(brm, (float)gv[q], s1g); s2g = fmaf(bom, (float)gv[q], s2g);
      s1c = fmaf(brm, (float)cv[q], s1c); s2c = fmaf(bom, (float)cv[q], s2c);
    }
  }
#pragma unroll
  for (int o = 1; o < 16; o <<= 1) {
    s1g += __shfl_xor(s1g, o); s2g += __shfl_xor(s2g, o);
    s1c += __shfl_xor(s1c, o); s2c += __shfl_xor(s2c, o);
  }
  if (k16 == 0) {
    bgr[n * 512 + og] = bg[n * 512 + og] + s1g; vg2[n * 512 + og] = s2g;
    bcr[n * 512 + og] = bc[n * 512 + og] + s1c; vc2[n * 512 + og] = s2c;
  }
}

// ---------------- fused conv1(MFMA)+conv2(MFMA)+pool: one block per (b,e)
// R15's verified form: LDS 53,632 B, 3 blocks/CU, 9-tap single-buffer.
__global__ __launch_bounds__(256) void convfused_kernel(
    const f16* __restrict__ xp16, const f16* __restrict__ w1p, const float* __restrict__ b1,
    const f16* __restrict__ w2p, const float* __restrict__ b2, f16* __restrict__ pooled16)
{
  __shared__ __align__(16) char lds[53632];
  f16* xpatch = (f16*)lds;
  f16* AsubS = (f16*)lds;
  float* red = (float*)lds;
  float* bs1 = (float*)(lds + 16384);   // 256B
  f16* h1s = (f16*)(lds + 16640);       // 36,992B [289 pix][64 ci] swizzled
  f16* ws1 = (f16*)(lds + 16640);       // 4KB alias inside h1s (ph0-1)

  int b = blockIdx.x, e = blockIdx.y;
  int t = threadIdx.x, w = t >> 6, l = t & 63;

  const f16* xb = xp16 + (long)b * 8192;
#pragma unroll
  for (int c = 0; c < 4; c++)
    GLOAD_LDS16(xb + (w * 4 + c) * 512 + l * 8, &xpatch[(w * 4 + c) * 512]);
  GLOAD_LDS16(w1p + (long)e * 2048 + w * 512 + l * 8, &ws1[w * 512]);
  if (t < 64) bs1[t] = b1[e * 64 + t];
  asm volatile("s_waitcnt vmcnt(0)" ::: "memory");
  __syncthreads();

  // ph1: conv1 MFMA
  {
    int pw = w * 64;
    f16x8 a1[4], b1f[4];
#pragma unroll
    for (int i = 0; i < 4; i++)
      a1[i] = *(const f16x8*)&ws1[(l >> 4) * 512 + (i * 16 + (l & 15)) * 8];
#pragma unroll
    for (int jj = 0; jj < 4; jj++)
      b1f[jj] = *(const f16x8*)&xpatch[(l >> 4) * 2048 + (pw + jj * 16 + (l & 15)) * 8];
    __syncthreads();
    f32x4 acc1[4][4];
#pragma unroll
    for (int i = 0; i < 4; i++)
#pragma unroll
      for (int jj = 0; jj < 4; jj++)
        acc1[i][jj] = __builtin_amdgcn_mfma_f32_16x16x32_f16(
            a1[i], b1f[jj], (f32x4){0.f, 0.f, 0.f, 0.f}, 0, 0, 0);
#pragma unroll
    for (int i = 0; i < 4; i++) {
      int co0 = i * 16 + ((l >> 4) << 2);
      float bi0 = bs1[co0], bi1 = bs1[co0 + 1], bi2 = bs1[co0 + 2], bi3 = bs1[co0 + 3];
#pragma unroll
      for (int jj = 0; jj < 4; jj++) {
        int p2 = pw + jj * 16 + (l & 15);
        int oy2 = p2 >> 4, ox2 = p2 & 15;
        int p = oy2 * 17 + ox2;
        int fs = ((ox2 >> 1) + oy2) & 7;
        int slot = (co0 >> 3) ^ fs;
        f16x4 v;
        v[0] = (f16)fmaxf(acc1[i][jj][0] + bi0, 0.f);
        v[1] = (f16)fmaxf(acc1[i][jj][1] + bi1, 0.f);
        v[2] = (f16)fmaxf(acc1[i][jj][2] + bi2, 0.f);
        v[3] = (f16)fmaxf(acc1[i][jj][3] + bi3, 0.f);
        *(f16x4*)&h1s[p * 64 + slot * 8 + (co0 & 7)] = v;
      }
    }
  }
  if (t < 33) {
    int gy = (t < 17) ? 16 : (t - 17);
    int gx = (t < 17) ? t : 16;
    int p = gy * 17 + gx;
    f16x8 zz = {};
#pragma unroll
    for (int g = 0; g < 8; g++) *(f16x8*)&h1s[p * 64 + g * 8] = zz;
  }

  // ph2: conv2 MFMA over 9 taps
  int waveR = w >> 1, waveC = w & 1;
  const f16* wbase = w2p + (long)e * 73728;
  f32x4 acc[4][2];
#pragma unroll
  for (int i = 0; i < 4; i++) {
    acc[i][0] = (f32x4){0.f, 0.f, 0.f, 0.f};
    acc[i][1] = (f32x4){0.f, 0.f, 0.f, 0.f};
  }
  for (int tap = 0; tap < 9; tap++) {
    __syncthreads();
#pragma unroll
    for (int c = 0; c < 4; c++) {
      int ch = w * 4 + c;
      int co = ch * 8 + (l >> 3);
      int g = (l & 7) ^ (co & 7);
      GLOAD_LDS16(wbase + ((long)co * 9 + tap) * 64 + g * 8, &AsubS[ch * 512]);
    }
    asm volatile("s_waitcnt vmcnt(0)" ::: "memory");
    __syncthreads();
    int ky = tap / 3, kx = tap - ky * 3;
#pragma unroll
    for (int kk = 0; kk < 2; kk++) {
      f16x8 af[4], bf[2];
#pragma unroll
      for (int i = 0; i < 4; i++) {
        int row = waveR * 64 + i * 16 + (l & 15);
        int blk = (kk * 4 + (l >> 4)) ^ (row & 7);
        af[i] = *(const f16x8*)&AsubS[row * 64 + blk * 8];
      }
#pragma unroll
      for (int j = 0; j < 2; j++) {
        int sp = waveC * 32 + j * 16 + (l & 15);
        int iy = (sp >> 3) * 2 + ky, ix = (sp & 7) * 2 + kx;
        int fs = ((ix >> 1) + iy) & 7;
        int blk = (kk * 4 + (l >> 4)) ^ fs;
        bf[j] = *(const f16x8*)&h1s[(iy * 17 + ix) * 64 + blk * 8];
      }
#pragma unroll
      for (int i = 0; i < 4; i++)
#pragma unroll
        for (int j = 0; j < 2; j++)
          acc[i][j] = __builtin_amdgcn_mfma_f32_16x16x32_f16(af[i], bf[j], acc[i][j], 0, 0, 0);
    }
  }
  __syncthreads();
  const float* bn2 = b2 + e * 128;
#pragma unroll
  for (int i = 0; i < 4; i++) {
#pragma unroll
    for (int reg = 0; reg < 4; reg++) {
      int row = waveR * 64 + i * 16 + ((l >> 4) << 2) + reg;
      float bi = bn2[row];
      float s = fmaxf(acc[i][0][reg] + bi, 0.f) + fmaxf(acc[i][1][reg] + bi, 0.f);
      s += __shfl_xor(s, 1); s += __shfl_xor(s, 2);
      s += __shfl_xor(s, 4); s += __shfl_xor(s, 8);
      if ((l & 15) == 0) red[waveC * 128 + row] = s;
    }
  }
  __syncthreads();
  if (t < 128) {
    float v = (red[t] + red[128 + t]) * (1.f / 64.f);
    pooled16[((long)e * 256 + b) * 128 + t] = (f16)v;
  }
}

// ---------------- segmented f16-MFMA GEMM: MRx64 tile, 4 waves, per-seg outputs
struct SegsM {
  const f16* BT[4];
  const float* bias[4];
  f16* o16[4];
  f16* o16b[4];
  float* o32[4];
  long sBT[4], sBias[4], sO16[4], sO32[4];
  int ldo16[4], ldo32[4], act[4], segCols[4];
};

template <int MR>
__global__ __launch_bounds__(256) void gemmf16_kernel(
    const f16* __restrict__ A, long sA, int lda, SegsM segs, int K)
{
  constexpr int IW = MR / 32;
  __shared__ __align__(16) f16 Asub[2][MR * 64];
  __shared__ __align__(16) f16 Bsub[2][4096];
  int z = blockIdx.z;
  int rowBase = blockIdx.y * MR;
  int vcBase = blockIdx.x * 64;
  int seg = vcBase >> 9;
  int lcBase = vcBase & 511;
  const f16* An = A + (long)z * sA + (long)rowBase * lda;
  const f16* BTn = segs.BT[seg] + (long)z * segs.sBT[seg] + (long)lcBase * K;
  const float* biasN = segs.bias[seg] ? segs.bias[seg] + (long)z * segs.sBias[seg] : nullptr;
  int act = segs.act[seg];
  int segCols = segs.segCols[seg];
  int t = threadIdx.x, w = t >> 6, l = t & 63;
  int waveR = w >> 1, waveC = w & 1;
  f32x4 acc[IW][2];
#pragma unroll
  for (int i = 0; i < IW; i++) {
    acc[i][0] = (f32x4){0.f, 0.f, 0.f, 0.f};
    acc[i][1] = (f32x4){0.f, 0.f, 0.f, 0.f};
  }
  auto stage = [&](int buf, int kt) {
    int k0 = kt << 6;
#pragma unroll
    for (int c = 0; c < MR / 32; c++) {
      int ch = w * (MR / 32) + c;
      int row = ch * 8 + (l >> 3);
      int g = (l & 7) ^ (row & 7);
      GLOAD_LDS16(An + (long)row * lda + k0 + g * 8, &Asub[buf][ch * 512]);
    }
#pragma unroll
    for (int c = 0; c < 2; c++) {
      int ch = w * 2 + c;
      int col = ch * 8 + (l >> 3);
      int g = (l & 7) ^ (col & 7);
      GLOAD_LDS16(BTn + (long)col * K + k0 + g * 8, &Bsub[buf][ch * 512]);
    }
  };
  int nk = K >> 6;
  stage(0, 0);
  asm volatile("s_waitcnt vmcnt(0)" ::: "memory");
  __syncthreads();
  int cur = 0;
  for (int kt = 0; kt < nk; kt++) {
    if (kt + 1 < nk) stage(cur ^ 1, kt + 1);
#pragma unroll
    for (int kk = 0; kk < 2; kk++) {
      f16x8 af[IW], bf[2];
#pragma unroll
      for (int i = 0; i < IW; i++) {
        int row = waveR * (MR / 2) + i * 16 + (l & 15);
        int blk = (kk * 4 + (l >> 4)) ^ (row & 7);
        af[i] = *(const f16x8*)&Asub[cur][row * 64 + blk * 8];
      }
#pragma unroll
      for (int j = 0; j < 2; j++) {
        int col = waveC * 32 + j * 16 + (l & 15);
        int blk = (kk * 4 + (l >> 4)) ^ (col & 7);
        bf[j] = *(const f16x8*)&Bsub[cur][col * 64 + blk * 8];
      }
#pragma unroll
      for (int i = 0; i < IW; i++)
#pragma unroll
        for (int j = 0; j < 2; j++)
          acc[i][j] = __builtin_amdgcn_mfma_f32_16x16x32_f16(af[i], bf[j], acc[i][j], 0, 0, 0);
    }
    if (kt + 1 < nk) {
      asm volatile("s_waitcnt vmcnt(0)" ::: "memory");
      __syncthreads();
      cur ^= 1;
    }
  }
  f16* o16 = segs.o16[seg];
  f16* o16b = segs.o16b[seg];
  float* o32 = segs.o32[seg];
  long sO16 = segs.sO16[seg], sO32 = segs.sO32[seg];
  int ldo16 = segs.ldo16[seg], ldo32 = segs.ldo32[seg];
#pragma unroll
  for (int i = 0; i < IW; i++) {
    int rb = rowBase + waveR * (MR / 2) + i * 16 + ((l >> 4) << 2);
#pragma unroll
    for (int j = 0; j < 2; j++) {
      int lc = lcBase + waveC * 32 + j * 16 + (l & 15);
      if (lc >= segCols) continue;
      float bv = biasN ? biasN[lc] : 0.f;
#pragma unroll
      for (int reg = 0; reg < 4; reg++) {
        float v = acc[i][j][reg] + bv;
        if (act == 1) v = fmaxf(v, 0.f);
        else if (act == 2) v = 1.f / (1.f + __expf(-v));
        else if (act == 3) v = tanhf(v);
        long rr = rb + reg;
        if (o16) o16[(long)z * sO16 + rr * ldo16 + lc] = (f16)v;
        if (o16b) o16b[(long)z * sO16 + rr * ldo16 + lc] = (f16)v;
        if (o32) o32[(long)z * sO32 + rr * ldo32 + lc] = v;
      }
    }
  }
}

// ---------------- per-step fused GRU + gates + 8-node attention (512 threads)
__global__ __launch_bounds__(512) void step_kernel(
    const f16* __restrict__ qkv16, const float* __restrict__ gi32,
    const float* __restrict__ wh, const float* __restrict__ bh,
    float* __restrict__ cs, const float* __restrict__ sw, const float* __restrict__ sb,
    const float* __restrict__ rw, const float* __restrict__ rb,
    const float* __restrict__ aw, const float* __restrict__ abb,
    const float* __restrict__ edge,
    float* __restrict__ msgsum32, f16* __restrict__ msgsum16, int step)
{
  int b = blockIdx.x, t = threadIdx.x;
  __shared__ float qs[8 * 520], ks[8 * 520];
  __shared__ f16 vs16[8 * 520];
  __shared__ float csh[512];
  __shared__ float sc[512];
  __shared__ float se[8], re[8], edg[64], abl[64];

  for (int i = t; i < 2048; i += 512) {
    int nn = i >> 8, c2 = (i & 255) * 2;
    int h = c2 >> 6, d = c2 & 63;
    long base = ((long)nn * 256 + b) * 1536 + c2;
    int la = nn * 520 + h * 65 + d;
    f16x2 qv = *(const f16x2*)&qkv16[base];
    f16x2 kv = *(const f16x2*)&qkv16[base + 512];
    *(f16x2*)&vs16[la] = *(const f16x2*)&qkv16[base + 1024];
    qs[la] = (float)qv[0]; qs[la + 1] = (float)qv[1];
    ks[la] = (float)kv[0]; ks[la + 1] = (float)kv[1];
  }
  if (t >= 448) edg[t - 448] = edge[t - 448];
  int n = t >> 6, hc = t & 63;
  if (step > 0) csh[t] = cs[((long)n * 256 + b) * 64 + hc];
  __syncthreads();

  float c0 = (step > 0) ? csh[t] : 0.f;
  float g0 = bh[n * 192 + hc], g1 = bh[n * 192 + 64 + hc], g2 = bh[n * 192 + 128 + hc];
  if (step > 0) {
    const float* whn = wh + (long)n * 12288;
    for (int k = 0; k < 64; k++) {
      float cv = csh[n * 64 + k];
      g0 = fmaf(cv, whn[k * 192 + hc], g0);
      g1 = fmaf(cv, whn[k * 192 + 64 + hc], g1);
      g2 = fmaf(cv, whn[k * 192 + 128 + hc], g2);
    }
  }
  const float* gi = gi32 + ((long)n * 256 + b) * 192;
  float zg = 1.f / (1.f + __expf(-(gi[hc] + g0)));
  float rg = 1.f / (1.f + __expf(-(gi[64 + hc] + g1)));
  float ng = tanhf(gi[128 + hc] + rg * g2);
  float cn = (1.f - zg) * ng + zg * c0;
  cs[((long)n * 256 + b) * 64 + hc] = cn;
  {
    float ps = cn * sw[n * 64 + hc];
    float pr = cn * rw[n * 64 + hc];
#pragma unroll
    for (int o = 32; o; o >>= 1) { ps += __shfl_xor(ps, o); pr += __shfl_xor(pr, o); }
    if (hc == 0) {
      se[n] = 1.f / (1.f + __expf(-(ps + sb[n])));
      re[n] = 1.f / (1.f + __expf(-(pr + rb[n])));
    }
#pragma unroll
    for (int kk = 0; kk < 8; kk++) {
      float pa = cn * aw[(n * 64 + hc) * 8 + kk];
#pragma unroll
      for (int o = 32; o; o >>= 1) pa += __shfl_xor(pa, o);
      if (hc == 0) abl[n * 8 + kk] = pa + abb[n * 8 + kk];
    }
  }
  __syncthreads();

  {
    int i = t >> 6, j = (t >> 3) & 7, h = t & 7;
    const float* qp = &qs[i * 520 + h * 65];
    const float* kp = &ks[j * 520 + h * 65];
    float s = 0.f;
#pragma unroll
    for (int d = 0; d < 64; d++) s = fmaf(qp[d], kp[d], s);
    sc[t] = s * 0.125f + edg[i * 8 + j] + abl[i * 8 + h];
  }
  __syncthreads();
  if (t < 64) {
    int i = t >> 3, h = t & 7;
    float mx = -1e30f;
#pragma unroll
    for (int j = 0; j < 8; j++) mx = fmaxf(mx, sc[(i << 6) + (j << 3) + h]);
    float e[8], sm = 0.f;
#pragma unroll
    for (int j = 0; j < 8; j++) { e[j] = __expf(sc[(i << 6) + (j << 3) + h] - mx); sm += e[j]; }
    float inv = re[i] / sm;
#pragma unroll
    for (int j = 0; j < 8; j++) sc[(i << 6) + (j << 3) + h] = e[j] * inv * se[j];
  }
  __syncthreads();
  for (int idx = t; idx < 4096; idx += 512) {
    int i = idx >> 9, c = idx & 511, h = c >> 6, d = c & 63;
    float s = 0.f;
#pragma unroll
    for (int j = 0; j < 8; j++)
      s = fmaf(sc[(i << 6) + (j << 3) + h], (float)vs16[j * 520 + h * 65 + d], s);
    long oi = ((long)i * 256 + b) * 512 + c;
    float nv = (step == 0) ? s : (msgsum32[oi] + s);
    msgsum32[oi] = nv;
    msgsum16[oi] = (f16)nv;
  }
}

// ---------------- fused gate GEMM + h-update (64-row tiles)
__global__ __launch_bounds__(256) void gatefused_kernel(
    const f16* __restrict__ h16cur, const f16* __restrict__ feats16,
    const f16* __restrict__ msgsum16,
    const f16* __restrict__ wgT, const f16* __restrict__ wcT,
    const f16* __restrict__ WeffGT, const f16* __restrict__ WeffCT,
    const float* __restrict__ bgr, const float* __restrict__ vg2,
    const float* __restrict__ bcr, const float* __restrict__ vc2,
    float* __restrict__ h32, f16* __restrict__ h16next, float tp1)
{
  __shared__ __align__(16) f16 Asub[2][4096];
  __shared__ __align__(16) f16 Bgs[2][4096];
  __shared__ __align__(16) f16 Bcs[2][4096];
  int z = blockIdx.z;
  int rowBase = blockIdx.y * 64;
  int colBase = blockIdx.x * 64;
  int t = threadIdx.x, w = t >> 6, l = t & 63;
  int waveR = w >> 1, waveC = w & 1;
  f32x4 accG[2][2], accC[2][2];
#pragma unroll
  for (int i = 0; i < 2; i++)
#pragma unroll
    for (int j = 0; j < 2; j++) {
      accG[i][j] = (f32x4){0.f, 0.f, 0.f, 0.f};
      accC[i][j] = (f32x4){0.f, 0.f, 0.f, 0.f};
    }

  auto stage = [&](int buf, int kt) {
    const f16* asrc;
    if (kt < 8)       asrc = h16cur  + (long)z * 131072 + kt * 64;
    else if (kt < 16) asrc = feats16 + (long)z * 131072 + (kt - 8) * 64;
    else              asrc = msgsum16 + (long)z * 131072 + (kt - 16) * 64;
#pragma unroll
    for (int c = 0; c < 2; c++) {
      int ch = w * 2 + c;
      int row = ch * 8 + (l >> 3);
      int g = (l & 7) ^ (row & 7);
      GLOAD_LDS16(asrc + (long)(rowBase + row) * 512 + g * 8, &Asub[buf][ch * 512]);
    }
#pragma unroll
    for (int c = 0; c < 2; c++) {
      int ch = w * 2 + c;
      int cl = ch * 8 + (l >> 3);
      int g = (l & 7) ^ (cl & 7);
      const f16 *bgsrc, *bcsrc;
      if (kt < 16) {
        bgsrc = wgT + (long)z * 786432 + (long)(colBase + cl) * 1536 + kt * 64 + g * 8;
        bcsrc = wcT + (long)z * 786432 + (long)(colBase + cl) * 1536 + kt * 64 + g * 8;
      } else {
        bgsrc = WeffGT + (long)z * 262144 + (long)(colBase + cl) * 512 + (kt - 16) * 64 + g * 8;
        bcsrc = WeffCT + (long)z * 262144 + (long)(colBase + cl) * 512 + (kt - 16) * 64 + g * 8;
      }
      GLOAD_LDS16(bgsrc, &Bgs[buf][ch * 512]);
      GLOAD_LDS16(bcsrc, &Bcs[buf][ch * 512]);
    }
  };
  stage(0, 0);
  asm volatile("s_waitcnt vmcnt(0)" ::: "memory");
  __syncthreads();
  int cur = 0;
  for (int kt = 0; kt < 24; kt++) {
    if (kt + 1 < 24) stage(cur ^ 1, kt + 1);
#pragma unroll
    for (int kk = 0; kk < 2; kk++) {
      f16x8 af[2], bgf[2], bcf[2];
#pragma unroll
      for (int i = 0; i < 2; i++) {
        int row = waveR * 32 + i * 16 + (l & 15);
        int blk = (kk * 4 + (l >> 4)) ^ (row & 7);
        af[i] = *(const f16x8*)&Asub[cur][row * 64 + blk * 8];
      }
#pragma unroll
      for (int j = 0; j < 2; j++) {
        int cl = waveC * 32 + j * 16 + (l & 15);
        int blk = (kk * 4 + (l >> 4)) ^ (cl & 7);
        bgf[j] = *(const f16x8*)&Bgs[cur][cl * 64 + blk * 8];
        bcf[j] = *(const f16x8*)&Bcs[cur][cl * 64 + blk * 8];
      }
#pragma unroll
      for (int i = 0; i < 2; i++)
#pragma unroll
        for (int j = 0; j < 2; j++) {
          accG[i][j] = __builtin_amdgcn_mfma_f32_16x16x32_f16(af[i], bgf[j], accG[i][j], 0, 0, 0);
          accC[i][j] = __builtin_amdgcn_mfma_f32_16x16x32_f16(af[i], bcf[j], accC[i][j], 0, 0, 0);
        }
    }
    if (kt + 1 < 24) {
      asm volatile("s_waitcnt vmcnt(0)" ::: "memory");
      __syncthreads();
      cur ^= 1;
    }
  }
#pragma unroll
  for (int i = 0; i < 2; i++) {
    int rb = rowBase + waveR * 32 + i * 16 + ((l >> 4) << 2);
#pragma unroll
    for (int j = 0; j < 2; j++) {
      int col = colBase + waveC * 32 + j * 16 + (l & 15);
      float bG = bgr[z * 512 + col] + tp1 * vg2[z * 512 + col];
      float bC = bcr[z * 512 + col] + tp1 * vc2[z * 512 + col];
#pragma unroll
      for (int reg = 0; reg < 4; reg++) {
        int row = rb + reg;
        float g = 1.f / (1.f + __expf(-(accG[i][j][reg] + bG)));
        float cd = tanhf(accC[i][j][reg] + bC);
        long hidx = ((long)z * 256 + row) * 512 + col;
        float h = h32[hidx];
        float nh = (1.f - g) * h + g * cd;
        h32[hidx] = nh;
        h16next[hidx] = (f16)nh;
      }
    }
  }
}

extern "C" void kernel_launch(void* const* d_in, const int* in_sizes, int n_in,
                              void* d_out, int out_size, void* d_ws, size_t ws_size,
                              hipStream_t stream)
{
  (void)in_sizes; (void)n_in; (void)out_size;
  const float* x        = (const float*)d_in[0];
  const float* conv1_w  = (const float*)d_in[1];
  const float* conv1_b  = (const float*)d_in[2];
  const float* conv2_w  = (const float*)d_in[3];
  const float* conv2_b  = (const float*)d_in[4];
  const float* feat_w   = (const float*)d_in[5];
  const float* feat_b   = (const float*)d_in[6];
  const float* ctrl_wi  = (const float*)d_in[7];
  const float* ctrl_wh  = (const float*)d_in[8];
  const float* ctrl_bi  = (const float*)d_in[9];
  const float* ctrl_bh  = (const float*)d_in[10];
  const float* send_w   = (const float*)d_in[11];
  const float* send_b   = (const float*)d_in[12];
  const float* recv_w   = (const float*)d_in[13];
  const float* recv_b   = (const float*)d_in[14];
  const float* abias_w  = (const float*)d_in[15];
  const float* abias_b  = (const float*)d_in[16];
  const float* wq       = (const float*)d_in[17];
  const float* wk       = (const float*)d_in[18];
  const float* wv       = (const float*)d_in[19];
  const float* wo       = (const float*)d_in[20];
  const float* bo       = (const float*)d_in[21];
  const float* edge     = (const float*)d_in[22];
  const float* wr       = (const float*)d_in[23];
  const float* br       = (const float*)d_in[24];
  const float* wg       = (const float*)d_in[25];
  const float* bg       = (const float*)d_in[26];
  const float* wc       = (const float*)d_in[27];
  const float* bc       = (const float*)d_in[28];
  const float* wcls     = (const float*)d_in[29];
  const float* bcls     = (const float*)d_in[30];

  // ---- workspace layout
  float* f32b = (float*)d_ws;
  float* h32      = f32b;             // 1,048,576
  float* gi32     = f32b + 1048576;   //   393,216
  float* msgsum32 = f32b + 1441792;   // 1,048,576
  float* cs       = f32b + 2490368;   //   131,072
  float* bor32    = f32b + 2621440;   //     4,096
  float* bgr      = f32b + 2625536;   //     4,096
  float* vg2b     = f32b + 2629632;   //     4,096
  float* bcr      = f32b + 2633728;   //     4,096
  float* vc2b     = f32b + 2637824;   //     4,096
  f16* hb = (f16*)(f32b + 2641920);
  f16* pooled16 = hb;                 //   262,144
  f16* h16a     = hb + 262144;        // 1,048,576
  f16* h16b     = hb + 1310720;       // 1,048,576
  f16* feats16  = hb + 2359296;       // 1,048,576
  f16* msgsum16 = hb + 3407872;       // 1,048,576
  f16* qkv16    = hb + 4456448;       // 3,145,728
  f16* wqT      = hb + 7602176;       // 6,291,456 (wq|wk|wv)
  f16* wiT      = hb + 13893632;      //   786,432
  f16* featwT   = hb + 14680064;      //   524,288
  f16* wrT      = hb + 15204352;      // 2,097,152 (x0.125)
  f16* wgT      = hb + 17301504;      // 6,291,456 (wcT contiguous)
  f16* wcT      = hb + 23592960;      // 6,291,456
  f16* c2wp     = hb + 29884416;      //   589,824
  f16* wo16     = hb + 30474240;      // 2,097,152
  f16* P        = hb + 32571392;      // 2,097,152
  f16* P2       = hb + 34668544;      // 2,097,152
  f16* WeffGT   = hb + 36765696;      // 2,097,152
  f16* WeffCT   = hb + 38862848;      // 2,097,152
  f16* w1p      = hb + 40960000;      //    16,384
  f16* xp16     = hb + 40976384;      // 2,097,152
  f16* wclsT    = hb + 43073536;      //   524,288
  // total = 10,567,680 + 87,195,648 = 97,763,328 B
  if (ws_size < 97763328ull) return;

  f16* hbuf[2] = {h16a, h16b};

  // ---- prep (17 launches total)
  twall_kernel<<<dim3(8, 24, 64), 256, 0, stream>>>(
      wq, wk, wv, ctrl_wi, wr, feat_w, wg, wc, wqT, wiT, wrT, featwT, wgT);
  smallprep_kernel<<<4160, 256, 0, stream>>>(wo, wo16, conv2_w, c2wp, conv1_w, w1p,
                                             wcls, wclsT, x, xp16);
  borprep2_kernel<<<dim3(32, 8), 256, 0, stream>>>(wrT, bo, bor32);
  biasfold2_kernel<<<dim3(32, 8), 256, 0, stream>>>(wgT, wcT, bg, bc, br, bor32,
                                                    bgr, vg2b, bcr, vc2b);
  // P[c][m] = sum_k wo[c][k]*wr[k][m]/8  (mirror into P2 for z=8..15 reads)
  {
    SegsM s{};
    s.BT[0] = wrT; s.sBT[0] = 262144;
    s.o16[0] = P; s.o16b[0] = P2; s.sO16[0] = 262144; s.ldo16[0] = 512;
    s.segCols[0] = 512;
    gemmf16_kernel<64><<<dim3(8, 8, 8), 256, 0, stream>>>(wo16, 262144L, 512, s, 512);
  }
  // Weff{G,C}T[o][c] = sum_m wg/wc_r[m][o]*P[c][m]
  {
    SegsM s{};
    s.BT[0] = P; s.sBT[0] = 262144;
    s.o16[0] = WeffGT; s.sO16[0] = 262144; s.ldo16[0] = 512;
    s.segCols[0] = 512;
    gemmf16_kernel<64><<<dim3(8, 8, 16), 256, 0, stream>>>(wgT + 1024, 786432L, 1536, s, 512);
  }

  // ---- feature extraction -> pooled16
  convfused_kernel<<<dim3(256, 8), 256, 0, stream>>>(xp16, w1p, conv1_b, c2wp, conv2_b, pooled16);

  // feats = relu(pooled @ feat_w + b) -> feats16; h-init -> h16a + h32
  {
    SegsM s{};
    s.BT[0] = featwT; s.sBT[0] = 65536; s.bias[0] = feat_b; s.sBias[0] = 512; s.act[0] = 1;
    s.o16[0] = feats16; s.o16b[0] = h16a; s.sO16[0] = 131072; s.ldo16[0] = 512;
    s.o32[0] = h32; s.sO32[0] = 131072; s.ldo32[0] = 512;
    s.segCols[0] = 512;
    gemmf16_kernel<128><<<dim3(8, 2, 8), 256, 0, stream>>>(pooled16, 32768L, 128, s, 128);
  }

  for (int step = 0; step < 3; step++) {
    // q|k|v (f16) + gi (f32) = h @ {wq,wk,wv,ctrl_wi}
    {
      SegsM s{};
      s.BT[0] = wqT;            s.sBT[0] = 262144;
      s.BT[1] = wqT + 2097152;  s.sBT[1] = 262144;
      s.BT[2] = wqT + 4194304;  s.sBT[2] = 262144;
      s.BT[3] = wiT;            s.sBT[3] = 98304;
      s.bias[3] = ctrl_bi; s.sBias[3] = 192;
      s.o16[0] = qkv16;        s.sO16[0] = 393216; s.ldo16[0] = 1536;
      s.o16[1] = qkv16 + 512;  s.sO16[1] = 393216; s.ldo16[1] = 1536;
      s.o16[2] = qkv16 + 1024; s.sO16[2] = 393216; s.ldo16[2] = 1536;
      s.o32[3] = gi32; s.sO32[3] = 49152; s.ldo32[3] = 192;
      s.segCols[0] = 512; s.segCols[1] = 512; s.segCols[2] = 512; s.segCols[3] = 192;
      gemmf16_kernel<128><<<dim3(27, 2, 8), 256, 0, stream>>>(hbuf[step & 1], 131072L, 512, s, 512);
    }
    step_kernel<<<256, 512, 0, stream>>>(
        qkv16, gi32, ctrl_wh, ctrl_bh, cs, send_w, send_b, recv_w, recv_b,
        abias_w, abias_b, edge, msgsum32, msgsum16, step);
    gatefused_kernel<<<dim3(8, 4, 8), 256, 0, stream>>>(
        hbuf[step & 1], feats16, msgsum16, wgT, wcT, WeffGT, WeffCT,
        bgr, vg2b, bcr, vc2b, h32, hbuf[(step + 1) & 1], (float)(step + 1));
  }
  // classifier: logits = h @ wclsT + bcls (f16 MFMA, fp32 out)
  {
    SegsM s{};
    s.BT[0] = wclsT; s.sBT[0] = 65536;
    s.bias[0] = bcls; s.sBias[0] = 100;
    s.o32[0] = (float*)d_out; s.sO32[0] = 25600; s.ldo32[0] = 100;
    s.segCols[0] = 100;
    gemmf16_kernel<128><<<dim3(2, 2, 8), 256, 0, stream>>>(hbuf[1], 131072L, 512, s, 512);
  }
}